// Round 11
// baseline (277.181 us; speedup 1.0000x reference)
//
#include <hip/hip_runtime.h>
#include <hip/hip_bf16.h>

typedef __bf16 bf16x8 __attribute__((ext_vector_type(8)));
typedef __bf16 bf16x4 __attribute__((ext_vector_type(4)));
typedef float f32x4 __attribute__((ext_vector_type(4)));

#define S_LEN 2048
#define BATCH 32
#define DIM   1024          // ENC_DIM = DEC_DIM
#define FAN   (2*DIM)

// round-to-nearest-even f32 -> bf16
__device__ __forceinline__ unsigned short f2bf(float f) {
    union { float f; unsigned u; } x; x.f = f;
    unsigned r = x.u + 0x7FFFu + ((x.u >> 16) & 1u);
    return (unsigned short)(r >> 16);
}

__device__ __forceinline__ float fast_tanh(float x) {
    float e = __expf(2.0f * x);
    return 1.0f - 2.0f / (e + 1.0f);
}

// XOR chunk swizzle on a [rows][128 bytes] LDS tile
__device__ __forceinline__ int swz(int row, int col) {   // col in bytes
    return row * 128 + (col ^ ((row & 7) << 4));
}

// async 16B global->LDS (LDS dest = wave-uniform base; HW adds lane*16)
__device__ __forceinline__ void gload16(const void* g, void* l) {
    __builtin_amdgcn_global_load_lds((const __attribute__((address_space(1))) void*)g,
                                     (__attribute__((address_space(3))) void*)l, 16, 0, 0);
}

// ---------------- fused prep: enc->bf16 stream + W2->bf16 + hw GEMV, one dispatch
// blocks [0,4096): enc2bf; [4096,5120): w2bf; [5120,6144): hw
__global__ __launch_bounds__(256) void k_prep(const float* __restrict__ enc,
                                              unsigned short* __restrict__ encbf,
                                              const float* __restrict__ attn_w,
                                              unsigned short* __restrict__ w2bf,
                                              const float* __restrict__ hidden,
                                              const float* __restrict__ attn_b,
                                              float* __restrict__ hw) {
    const int bid = blockIdx.x, tid = threadIdx.x;
    if (bid < 4096) {
        const size_t stride = (size_t)4096 * 256;
        const size_t n8 = (size_t)S_LEN * BATCH * DIM / 8;
        for (size_t i = (size_t)bid * 256 + tid; i < n8; i += stride) {
            float4 a = ((const float4*)enc)[2 * i];
            float4 b = ((const float4*)enc)[2 * i + 1];
            bf16x8 o;
            o[0] = (__bf16)a.x; o[1] = (__bf16)a.y; o[2] = (__bf16)a.z; o[3] = (__bf16)a.w;
            o[4] = (__bf16)b.x; o[5] = (__bf16)b.y; o[6] = (__bf16)b.z; o[7] = (__bf16)b.w;
            ((bf16x8*)encbf)[i] = o;
        }
    } else if (bid < 5120) {
        const int t = (bid - 4096) * 256 + tid;
        const int n  = t >> 8;
        const int k4 = (t & 255) * 4;
        float4 w = *(const float4*)(attn_w + (size_t)n * FAN + DIM + k4);
        ushort4 o;
        o.x = f2bf(w.x); o.y = f2bf(w.y); o.z = f2bf(w.z); o.w = f2bf(w.w);
        *(ushort4*)(w2bf + (size_t)n * DIM + k4) = o;
    } else {
        const int d = bid - 5120;
        const int lane = tid & 63, w = tid >> 6;
        const float* wrow = attn_w + (size_t)d * FAN + lane * 4;
        float4 wv[4];
        #pragma unroll
        for (int c = 0; c < 4; ++c) wv[c] = *(const float4*)(wrow + c * 256);
        const float bd = attn_b[d];
        #pragma unroll
        for (int bb = 0; bb < 8; ++bb) {
            const int b = w * 8 + bb;
            const float* hrow = hidden + (size_t)b * DIM + lane * 4;
            float s = 0.f;
            #pragma unroll
            for (int c = 0; c < 4; ++c) {
                float4 h = *(const float4*)(hrow + c * 256);
                s += wv[c].x*h.x + wv[c].y*h.y + wv[c].z*h.z + wv[c].w*h.w;
            }
            #pragma unroll
            for (int o = 32; o; o >>= 1) s += __shfl_xor(s, o);
            if (lane == 0) hw[(size_t)b * DIM + d] = s + bd;
        }
    }
}

// ---------------- 2-phase 128x64 main GEMM (occupancy-optimized), fused epilogue
// C[m][n] = encbf_row(m) . W2_row(n);
// partial[m, slot] = sum_{n in wave 32-col slice} v[n]*tanh(C[m][n] + hw[m&31][n])
__global__ __launch_bounds__(256, 5) void k_main(const unsigned short* __restrict__ encbf,
                                                 const unsigned short* __restrict__ w2bf,
                                                 const float* __restrict__ hw,
                                                 const float* __restrict__ vvec,
                                                 float* __restrict__ partials) {
    __shared__ unsigned char Asm[128 * 128];   // [128 rows][64 bf16], swizzled content
    __shared__ unsigned char Bsm[64 * 128];    // [ 64 rows][64 bf16]
    const int tid = threadIdx.x;

    // XCD-aware bijective remap: 16 blocks sharing an A-panel run on ONE XCD.
    const int x  = blockIdx.x & 7;        // XCD id
    const int ii = blockIdx.x >> 3;       // local sequence on XCD x
    const int nb = ii & 15;               // 16 N-blocks of 64 cols
    const int mb = ((ii >> 4) << 3) | x;  // 512 M-blocks, bijective (8192 % 8 == 0)
    const int m0 = mb * 128, n0 = nb * 64;
    const int lane = tid & 63, wid = tid >> 6;
    const int wr = wid >> 1, wc = wid & 1;   // 2x2 wave grid: 64 rows x 32 cols each

    // staging (pre-swizzled source): chunk covers 8 rows; lane l -> row8 = l>>3,
    // source 16B-slot = (l&7) ^ row8 (matches read-side XOR)
    const int row8 = lane >> 3, colx = (lane & 7) ^ row8;
    const unsigned short* asrc[4];   // A: 16 chunks, c = wid*4+p
    const unsigned short* bsrc[2];   // B:  8 chunks, c = wid*2+p
    #pragma unroll
    for (int p = 0; p < 4; ++p)
        asrc[p] = encbf + (size_t)(m0 + 8 * (wid * 4 + p) + row8) * DIM + colx * 8;
    #pragma unroll
    for (int p = 0; p < 2; ++p)
        bsrc[p] = w2bf + (size_t)(n0 + 8 * (wid * 2 + p) + row8) * DIM + colx * 8;

    f32x4 acc[4][2];
    #pragma unroll
    for (int i2 = 0; i2 < 4; ++i2)
        #pragma unroll
        for (int j = 0; j < 2; ++j) acc[i2][j] = (f32x4){0.f, 0.f, 0.f, 0.f};

    #pragma unroll 1
    for (int t = 0; t < 16; ++t) {
        __syncthreads();   // all waves done reading tile t-1
        #pragma unroll
        for (int p = 0; p < 4; ++p)
            gload16(asrc[p] + t * 64, (void*)&Asm[(wid * 4 + p) * 1024]);
        #pragma unroll
        for (int p = 0; p < 2; ++p)
            gload16(bsrc[p] + t * 64, (void*)&Bsm[(wid * 2 + p) * 1024]);
        __syncthreads();   // vmcnt(0): tile t fully in LDS

        const int lrow = lane & 15;
        const int kbyte0 = (lane >> 4) * 16;
        #pragma unroll
        for (int kk = 0; kk < 2; ++kk) {
            const int kbyte = kbyte0 + kk * 64;
            bf16x8 af[4], bfr[2];
            #pragma unroll
            for (int i2 = 0; i2 < 4; ++i2)
                af[i2] = *(const bf16x8*)(&Asm[swz(wr * 64 + i2 * 16 + lrow, kbyte)]);
            #pragma unroll
            for (int j = 0; j < 2; ++j)
                bfr[j] = *(const bf16x8*)(&Bsm[swz(wc * 32 + j * 16 + lrow, kbyte)]);
            #pragma unroll
            for (int i2 = 0; i2 < 4; ++i2)
                #pragma unroll
                for (int j = 0; j < 2; ++j)
                    acc[i2][j] = __builtin_amdgcn_mfma_f32_16x16x32_bf16(af[i2], bfr[j], acc[i2][j], 0, 0, 0);
        }
    }

    // fused epilogue: tanh + v-weighted reduce over this wave's 32 n-columns
    const int colg = lane & 15, rowg = lane >> 4;
    #pragma unroll
    for (int i2 = 0; i2 < 4; ++i2) {
        #pragma unroll
        for (int r = 0; r < 4; ++r) {
            const int m = m0 + wr * 64 + i2 * 16 + rowg * 4 + r;
            const float* hwrow = hw + (size_t)(m & 31) * DIM + n0 + wc * 32;
            const float* vrow  = vvec + n0 + wc * 32;
            float sumv = 0.f;
            #pragma unroll
            for (int j = 0; j < 2; ++j) {
                const int nl = j * 16 + colg;
                float pre = acc[i2][j][r] + hwrow[nl];
                sumv += vrow[nl] * fast_tanh(pre);
            }
            sumv += __shfl_xor(sumv, 1);
            sumv += __shfl_xor(sumv, 2);
            sumv += __shfl_xor(sumv, 4);
            sumv += __shfl_xor(sumv, 8);
            if (colg == 0) partials[(size_t)m * 32 + nb * 2 + wc] = sumv;
        }
    }
}

// ---------------- fallback main (f32 A in-kernel cvt) — used only if ws too small
// writes the 32-slot partials layout (even slots = data, odd slots zeroed)
__global__ __launch_bounds__(256) void k_main_f32(const float* __restrict__ enc,
                                                  const unsigned short* __restrict__ w2bf,
                                                  const float* __restrict__ hw,
                                                  const float* __restrict__ vvec,
                                                  float* __restrict__ partials) {
    __shared__ unsigned char AsmL[128 * 128];
    __shared__ unsigned char BsmL[2][128 * 128];
    const int tid = threadIdx.x;
    const int x  = blockIdx.x & 7;
    const int ii = blockIdx.x >> 3;
    const int nb = ii & 7;
    const int mb = ((ii >> 3) << 3) | x;
    const int m0 = mb * 128, n0 = nb * 128;
    const int lane = tid & 63, wid = tid >> 6;
    const int wr = wid >> 1, wc = wid & 1;
    const int ar = tid >> 4, ac = tid & 15;
    const float* aptr = enc + (size_t)(m0 + ar) * DIM + ac * 4;
    const int row8 = lane >> 3, colx = (lane & 7) ^ row8;
    const unsigned short* bsrc[4];
    #pragma unroll
    for (int p = 0; p < 4; ++p)
        bsrc[p] = w2bf + (size_t)(n0 + 8 * (wid * 4 + p) + row8) * DIM + colx * 8;

    f32x4 acc[4][4];
    #pragma unroll
    for (int i2 = 0; i2 < 4; ++i2)
        #pragma unroll
        for (int j = 0; j < 4; ++j) acc[i2][j] = (f32x4){0.f, 0.f, 0.f, 0.f};

    float4 areg[8];
    #pragma unroll
    for (int p = 0; p < 8; ++p) areg[p] = *(const float4*)(aptr + p * 16 * DIM);
    #pragma unroll
    for (int p = 0; p < 4; ++p)
        gload16(bsrc[p], (void*)&BsmL[0][(wid * 4 + p) * 1024]);

    #pragma unroll 1
    for (int t = 0; t < 16; ++t) {
        asm volatile("s_waitcnt lgkmcnt(0)" ::: "memory");
        __builtin_amdgcn_s_barrier();
        #pragma unroll
        for (int p = 0; p < 8; ++p) {
            bf16x4 c;
            c[0] = (__bf16)areg[p].x; c[1] = (__bf16)areg[p].y;
            c[2] = (__bf16)areg[p].z; c[3] = (__bf16)areg[p].w;
            *(bf16x4*)(&AsmL[swz(ar + p * 16, ac * 8)]) = c;
        }
        if (t + 1 < 16) {
            const int ko = (t + 1) * 64;
            #pragma unroll
            for (int p = 0; p < 8; ++p) areg[p] = *(const float4*)(aptr + ko + p * 16 * DIM);
            #pragma unroll
            for (int p = 0; p < 4; ++p)
                gload16(bsrc[p] + (size_t)(t + 1) * 64,
                        (void*)&BsmL[(t + 1) & 1][(wid * 4 + p) * 1024]);
            asm volatile("s_waitcnt vmcnt(12)" ::: "memory");
        } else {
            asm volatile("s_waitcnt vmcnt(0)" ::: "memory");
        }
        asm volatile("s_waitcnt lgkmcnt(0)" ::: "memory");
        __builtin_amdgcn_s_barrier();

        const unsigned char* bbase = &BsmL[t & 1][0];
        const int lrow = lane & 15;
        const int kbyte0 = (lane >> 4) * 16;
        #pragma unroll
        for (int kk = 0; kk < 2; ++kk) {
            const int kbyte = kbyte0 + kk * 64;
            bf16x8 af[4], bfr2[4];
            #pragma unroll
            for (int i2 = 0; i2 < 4; ++i2)
                af[i2] = *(const bf16x8*)(&AsmL[swz(wr * 64 + i2 * 16 + lrow, kbyte)]);
            #pragma unroll
            for (int j = 0; j < 4; ++j)
                bfr2[j] = *(const bf16x8*)(&bbase[swz(wc * 64 + j * 16 + lrow, kbyte)]);
            #pragma unroll
            for (int i2 = 0; i2 < 4; ++i2)
                #pragma unroll
                for (int j = 0; j < 4; ++j)
                    acc[i2][j] = __builtin_amdgcn_mfma_f32_16x16x32_bf16(af[i2], bfr2[j], acc[i2][j], 0, 0, 0);
        }
    }

    const int colg = lane & 15, rowg = lane >> 4;
    #pragma unroll
    for (int i2 = 0; i2 < 4; ++i2)
        #pragma unroll
        for (int r = 0; r < 4; ++r) {
            const int m = m0 + wr * 64 + i2 * 16 + rowg * 4 + r;
            const float* hwrow = hw + (size_t)(m & 31) * DIM + n0 + wc * 64;
            const float* vrow  = vvec + n0 + wc * 64;
            float sumv = 0.f;
            #pragma unroll
            for (int j = 0; j < 4; ++j) {
                const int nl = j * 16 + colg;
                float pre = acc[i2][j][r] + hwrow[nl];
                sumv += vrow[nl] * fast_tanh(pre);
            }
            sumv += __shfl_xor(sumv, 1);
            sumv += __shfl_xor(sumv, 2);
            sumv += __shfl_xor(sumv, 4);
            sumv += __shfl_xor(sumv, 8);
            if (colg == 0) {
                partials[(size_t)m * 32 + nb * 4 + wc * 2]     = sumv;
                partials[(size_t)m * 32 + nb * 4 + wc * 2 + 1] = 0.f;
            }
        }
}

// per-batch softmax over s (sums the 32 partials per (s,b) first); 1024 thr, 2 s each
__global__ __launch_bounds__(1024) void k_softmax(const float* __restrict__ partials,
                                                  float* __restrict__ out) {
    const int b = blockIdx.x;      // 32
    const int tid = threadIdx.x;   // 1024
    __shared__ float redm[16], reds[16];
    float loc[2];
    float mx = -1e30f;
    #pragma unroll
    for (int i = 0; i < 2; ++i) {
        const int s = tid + i * 1024;
        const float4* p = (const float4*)(partials + ((size_t)s * 32 + b) * 32);
        float v = 0.f;
        #pragma unroll
        for (int q = 0; q < 8; ++q) {
            float4 pq = p[q];
            v += (pq.x + pq.y) + (pq.z + pq.w);
        }
        loc[i] = v; mx = fmaxf(mx, v);
    }
    #pragma unroll
    for (int o = 32; o; o >>= 1) mx = fmaxf(mx, __shfl_xor(mx, o));
    const int wid2 = tid >> 6, lane = tid & 63;
    if (lane == 0) redm[wid2] = mx;
    __syncthreads();
    mx = redm[0];
    #pragma unroll
    for (int w = 1; w < 16; ++w) mx = fmaxf(mx, redm[w]);
    float sum = 0.f;
    #pragma unroll
    for (int i = 0; i < 2; ++i) { float e = __expf(loc[i] - mx); loc[i] = e; sum += e; }
    #pragma unroll
    for (int o = 32; o; o >>= 1) sum += __shfl_xor(sum, o);
    if (lane == 0) reds[wid2] = sum;
    __syncthreads();
    sum = 0.f;
    #pragma unroll
    for (int w = 0; w < 16; ++w) sum += reds[w];
    const float rs = 1.0f / sum;
    #pragma unroll
    for (int i = 0; i < 2; ++i) out[(size_t)b * S_LEN + tid + i * 1024] = loc[i] * rs;
}

extern "C" void kernel_launch(void* const* d_in, const int* in_sizes, int n_in,
                              void* d_out, int out_size, void* d_ws, size_t ws_size,
                              hipStream_t stream) {
    const float* hidden = (const float*)d_in[0];
    const float* enc    = (const float*)d_in[1];
    const float* attn_w = (const float*)d_in[2];
    const float* attn_b = (const float*)d_in[3];
    const float* v      = (const float*)d_in[4];
    float* out = (float*)d_out;

    char* ws = (char*)d_ws;
    float*          hw       = (float*)ws;                                   // 128 KiB
    unsigned short* w2bf     = (unsigned short*)(ws + (128u << 10));         // 2 MiB
    float*          partials = (float*)(ws + (128u << 10) + (2u << 20));     // 8 MiB (32 slots)
    unsigned short* encbf    = (unsigned short*)(ws + (128u << 10) + (10u << 20)); // 128 MiB
    const size_t NEED = (128u << 10) + (10u << 20) + ((size_t)S_LEN * BATCH * DIM * 2);

    if (ws_size >= NEED) {
        hipLaunchKernelGGL(k_prep, dim3(6144), dim3(256), 0, stream,
                           enc, encbf, attn_w, w2bf, hidden, attn_b, hw);
        hipLaunchKernelGGL(k_main, dim3(8192), dim3(256), 0, stream, encbf, w2bf, hw, v, partials);
    } else {
        hipLaunchKernelGGL(k_prep, dim3(6144), dim3(256), 0, stream,
                           enc, (unsigned short*)w2bf, attn_w, w2bf, hidden, attn_b, hw);
        hipLaunchKernelGGL(k_main_f32, dim3(4096), dim3(256), 0, stream, enc, w2bf, hw, v, partials);
    }
    hipLaunchKernelGGL(k_softmax, dim3(32), dim3(1024), 0, stream, partials, out);
}

// Round 12
// 242.748 us; speedup vs baseline: 1.1418x; 1.1418x over previous
//
#include <hip/hip_runtime.h>
#include <hip/hip_bf16.h>

typedef __bf16 bf16x8 __attribute__((ext_vector_type(8)));
typedef __bf16 bf16x4 __attribute__((ext_vector_type(4)));
typedef float f32x4 __attribute__((ext_vector_type(4)));

#define S_LEN 2048
#define BATCH 32
#define DIM   1024          // ENC_DIM = DEC_DIM
#define FAN   (2*DIM)

// round-to-nearest-even f32 -> bf16
__device__ __forceinline__ unsigned short f2bf(float f) {
    union { float f; unsigned u; } x; x.f = f;
    unsigned r = x.u + 0x7FFFu + ((x.u >> 16) & 1u);
    return (unsigned short)(r >> 16);
}

__device__ __forceinline__ float fast_tanh(float x) {
    float e = __expf(2.0f * x);
    return 1.0f - 2.0f / (e + 1.0f);
}

// XOR chunk swizzle on a [128 rows][128 bytes] LDS tile
__device__ __forceinline__ int swz(int row, int col) {   // col in bytes
    return row * 128 + (col ^ ((row & 7) << 4));
}

// async 16B global->LDS (LDS dest = wave-uniform base; HW adds lane*16)
__device__ __forceinline__ void gload16(const void* g, void* l) {
    __builtin_amdgcn_global_load_lds((const __attribute__((address_space(1))) void*)g,
                                     (__attribute__((address_space(3))) void*)l, 16, 0, 0);
}

// ---------------- fused prep: enc->bf16 stream + W2->bf16 + hw GEMV, one dispatch
// blocks [0,4096): enc2bf; [4096,5120): w2bf; [5120,6144): hw
__global__ __launch_bounds__(256) void k_prep(const float* __restrict__ enc,
                                              unsigned short* __restrict__ encbf,
                                              const float* __restrict__ attn_w,
                                              unsigned short* __restrict__ w2bf,
                                              const float* __restrict__ hidden,
                                              const float* __restrict__ attn_b,
                                              float* __restrict__ hw) {
    const int bid = blockIdx.x, tid = threadIdx.x;
    if (bid < 4096) {
        // ---- enc (f32, 64M elems) -> bf16, 8 elems/thread/iter, 8 iters
        const size_t stride = (size_t)4096 * 256;
        const size_t n8 = (size_t)S_LEN * BATCH * DIM / 8;
        for (size_t i = (size_t)bid * 256 + tid; i < n8; i += stride) {
            float4 a = ((const float4*)enc)[2 * i];
            float4 b = ((const float4*)enc)[2 * i + 1];
            bf16x8 o;
            o[0] = (__bf16)a.x; o[1] = (__bf16)a.y; o[2] = (__bf16)a.z; o[3] = (__bf16)a.w;
            o[4] = (__bf16)b.x; o[5] = (__bf16)b.y; o[6] = (__bf16)b.z; o[7] = (__bf16)b.w;
            ((bf16x8*)encbf)[i] = o;
        }
    } else if (bid < 5120) {
        // ---- W2bf[n][k] = bf16(attn_w[n, 1024+k]); 262144 threads x 4 elems
        const int t = (bid - 4096) * 256 + tid;
        const int n  = t >> 8;
        const int k4 = (t & 255) * 4;
        float4 w = *(const float4*)(attn_w + (size_t)n * FAN + DIM + k4);
        ushort4 o;
        o.x = f2bf(w.x); o.y = f2bf(w.y); o.z = f2bf(w.z); o.w = f2bf(w.w);
        *(ushort4*)(w2bf + (size_t)n * DIM + k4) = o;
    } else {
        // ---- hw[b][d] = dot(hidden[b,:], attn_w[d,0:1024]) + attn_b[d] (fp32)
        // one d per block; wave w handles b = 8w..8w+7; lanes split K
        const int d = bid - 5120;
        const int lane = tid & 63, w = tid >> 6;
        const float* wrow = attn_w + (size_t)d * FAN + lane * 4;
        float4 wv[4];
        #pragma unroll
        for (int c = 0; c < 4; ++c) wv[c] = *(const float4*)(wrow + c * 256);
        const float bd = attn_b[d];
        #pragma unroll
        for (int bb = 0; bb < 8; ++bb) {
            const int b = w * 8 + bb;
            const float* hrow = hidden + (size_t)b * DIM + lane * 4;
            float s = 0.f;
            #pragma unroll
            for (int c = 0; c < 4; ++c) {
                float4 h = *(const float4*)(hrow + c * 256);
                s += wv[c].x*h.x + wv[c].y*h.y + wv[c].z*h.z + wv[c].w*h.w;
            }
            #pragma unroll
            for (int o = 32; o; o >>= 1) s += __shfl_xor(s, o);
            if (lane == 0) hw[(size_t)b * DIM + d] = s + bd;
        }
    }
}

// ---------------- m97-replica main GEMM (both operands bf16 via global_load_lds)
// C[m][n] = encbf_row(m) . W2_row(n), fused epilogue:
// partial[m, slot] = sum_{n in wave-slice} v[n]*tanh(C[m][n] + hw[m&31][n])
__global__ __launch_bounds__(256, 4) void k_main(const unsigned short* __restrict__ encbf,
                                                 const unsigned short* __restrict__ w2bf,
                                                 const float* __restrict__ hw,
                                                 const float* __restrict__ vvec,
                                                 float* __restrict__ partials) {
    __shared__ unsigned char Asm[128 * 128];   // [128 rows][64 bf16], swizzled content
    __shared__ unsigned char Bsm[128 * 128];
    const int tid = threadIdx.x;

    // XCD-aware bijective remap: 8 blocks sharing an A-tile run on ONE XCD.
    const int x  = blockIdx.x & 7;        // XCD id
    const int ii = blockIdx.x >> 3;       // local sequence on XCD x
    const int nb = ii & 7;                // 8 N-blocks
    const int mb = ((ii >> 3) << 3) | x;  // 512 M-blocks, bijective (4096 % 8 == 0)
    const int m0 = mb * 128, n0 = nb * 128;
    const int lane = tid & 63, wid = tid >> 6;
    const int wr = wid >> 1, wc = wid & 1;

    // staging: chunk c = wid*4+p covers tile-rows 8c..8c+7; lane l -> row8 = l>>3,
    // pre-swizzled source 16B-slot = (l&7) ^ row8 (matches read-side XOR)
    const int row8 = lane >> 3, colx = (lane & 7) ^ row8;
    const unsigned short* asrc[4];
    const unsigned short* bsrc[4];
    #pragma unroll
    for (int p = 0; p < 4; ++p) {
        const int c = wid * 4 + p;
        asrc[p] = encbf + (size_t)(m0 + 8 * c + row8) * DIM + colx * 8;
        bsrc[p] = w2bf  + (size_t)(n0 + 8 * c + row8) * DIM + colx * 8;
    }

    f32x4 acc[4][4];
    #pragma unroll
    for (int i2 = 0; i2 < 4; ++i2)
        #pragma unroll
        for (int j = 0; j < 4; ++j) acc[i2][j] = (f32x4){0.f, 0.f, 0.f, 0.f};

    #pragma unroll 1
    for (int t = 0; t < 16; ++t) {
        __syncthreads();   // all waves done reading tile t-1
        #pragma unroll
        for (int p = 0; p < 4; ++p) {
            gload16(asrc[p] + t * 64, (void*)&Asm[(wid * 4 + p) * 1024]);
            gload16(bsrc[p] + t * 64, (void*)&Bsm[(wid * 4 + p) * 1024]);
        }
        __syncthreads();   // vmcnt(0): tile t fully in LDS

        const int lrow = lane & 15;
        const int kbyte0 = (lane >> 4) * 16;
        #pragma unroll
        for (int kk = 0; kk < 2; ++kk) {
            const int kbyte = kbyte0 + kk * 64;
            bf16x8 af[4], bfr[4];
            #pragma unroll
            for (int i2 = 0; i2 < 4; ++i2)
                af[i2] = *(const bf16x8*)(&Asm[swz(wr * 64 + i2 * 16 + lrow, kbyte)]);
            #pragma unroll
            for (int j = 0; j < 4; ++j)
                bfr[j] = *(const bf16x8*)(&Bsm[swz(wc * 64 + j * 16 + lrow, kbyte)]);
            #pragma unroll
            for (int i2 = 0; i2 < 4; ++i2)
                #pragma unroll
                for (int j = 0; j < 4; ++j)
                    acc[i2][j] = __builtin_amdgcn_mfma_f32_16x16x32_bf16(af[i2], bfr[j], acc[i2][j], 0, 0, 0);
        }
    }

    // fused epilogue: tanh + v-weighted reduce over this wave's 64 n-columns
    const int colg = lane & 15, rowg = lane >> 4;
    #pragma unroll
    for (int i2 = 0; i2 < 4; ++i2) {
        #pragma unroll
        for (int r = 0; r < 4; ++r) {
            const int m = m0 + wr * 64 + i2 * 16 + rowg * 4 + r;
            const float* hwrow = hw + (size_t)(m & 31) * DIM + n0 + wc * 64;
            const float* vrow  = vvec + n0 + wc * 64;
            float sumv = 0.f;
            #pragma unroll
            for (int j = 0; j < 4; ++j) {
                const int nl = j * 16 + colg;
                float pre = acc[i2][j][r] + hwrow[nl];
                sumv += vrow[nl] * fast_tanh(pre);
            }
            sumv += __shfl_xor(sumv, 1);
            sumv += __shfl_xor(sumv, 2);
            sumv += __shfl_xor(sumv, 4);
            sumv += __shfl_xor(sumv, 8);
            if (colg == 0) partials[(size_t)m * 16 + nb * 2 + wc] = sumv;
        }
    }
}

// ---------------- fallback main (f32 A in-kernel cvt) — used only if ws too small
__global__ __launch_bounds__(256) void k_main_f32(const float* __restrict__ enc,
                                                  const unsigned short* __restrict__ w2bf,
                                                  const float* __restrict__ hw,
                                                  const float* __restrict__ vvec,
                                                  float* __restrict__ partials) {
    __shared__ unsigned char AsmL[128 * 128];
    __shared__ unsigned char BsmL[2][128 * 128];
    const int tid = threadIdx.x;
    const int x  = blockIdx.x & 7;
    const int ii = blockIdx.x >> 3;
    const int nb = ii & 7;
    const int mb = ((ii >> 3) << 3) | x;
    const int m0 = mb * 128, n0 = nb * 128;
    const int lane = tid & 63, wid = tid >> 6;
    const int wr = wid >> 1, wc = wid & 1;
    const int ar = tid >> 4, ac = tid & 15;
    const float* aptr = enc + (size_t)(m0 + ar) * DIM + ac * 4;
    const int row8 = lane >> 3, colx = (lane & 7) ^ row8;
    const unsigned short* bsrc[4];
    #pragma unroll
    for (int p = 0; p < 4; ++p)
        bsrc[p] = w2bf + (size_t)(n0 + 8 * (wid * 4 + p) + row8) * DIM + colx * 8;

    f32x4 acc[4][4];
    #pragma unroll
    for (int i2 = 0; i2 < 4; ++i2)
        #pragma unroll
        for (int j = 0; j < 4; ++j) acc[i2][j] = (f32x4){0.f, 0.f, 0.f, 0.f};

    float4 areg[8];
    #pragma unroll
    for (int p = 0; p < 8; ++p) areg[p] = *(const float4*)(aptr + p * 16 * DIM);
    #pragma unroll
    for (int p = 0; p < 4; ++p)
        gload16(bsrc[p], (void*)&BsmL[0][(wid * 4 + p) * 1024]);

    #pragma unroll 1
    for (int t = 0; t < 16; ++t) {
        asm volatile("s_waitcnt lgkmcnt(0)" ::: "memory");
        __builtin_amdgcn_s_barrier();
        #pragma unroll
        for (int p = 0; p < 8; ++p) {
            bf16x4 c;
            c[0] = (__bf16)areg[p].x; c[1] = (__bf16)areg[p].y;
            c[2] = (__bf16)areg[p].z; c[3] = (__bf16)areg[p].w;
            *(bf16x4*)(&AsmL[swz(ar + p * 16, ac * 8)]) = c;
        }
        if (t + 1 < 16) {
            const int ko = (t + 1) * 64;
            #pragma unroll
            for (int p = 0; p < 8; ++p) areg[p] = *(const float4*)(aptr + ko + p * 16 * DIM);
            #pragma unroll
            for (int p = 0; p < 4; ++p)
                gload16(bsrc[p] + (size_t)(t + 1) * 64,
                        (void*)&BsmL[(t + 1) & 1][(wid * 4 + p) * 1024]);
            asm volatile("s_waitcnt vmcnt(12)" ::: "memory");
        } else {
            asm volatile("s_waitcnt vmcnt(0)" ::: "memory");
        }
        asm volatile("s_waitcnt lgkmcnt(0)" ::: "memory");
        __builtin_amdgcn_s_barrier();

        const unsigned char* bbase = &BsmL[t & 1][0];
        const int lrow = lane & 15;
        const int kbyte0 = (lane >> 4) * 16;
        #pragma unroll
        for (int kk = 0; kk < 2; ++kk) {
            const int kbyte = kbyte0 + kk * 64;
            bf16x8 af[4], bfr2[4];
            #pragma unroll
            for (int i2 = 0; i2 < 4; ++i2)
                af[i2] = *(const bf16x8*)(&AsmL[swz(wr * 64 + i2 * 16 + lrow, kbyte)]);
            #pragma unroll
            for (int j = 0; j < 4; ++j)
                bfr2[j] = *(const bf16x8*)(&bbase[swz(wc * 64 + j * 16 + lrow, kbyte)]);
            #pragma unroll
            for (int i2 = 0; i2 < 4; ++i2)
                #pragma unroll
                for (int j = 0; j < 4; ++j)
                    acc[i2][j] = __builtin_amdgcn_mfma_f32_16x16x32_bf16(af[i2], bfr2[j], acc[i2][j], 0, 0, 0);
        }
    }

    const int colg = lane & 15, rowg = lane >> 4;
    #pragma unroll
    for (int i2 = 0; i2 < 4; ++i2)
        #pragma unroll
        for (int r = 0; r < 4; ++r) {
            const int m = m0 + wr * 64 + i2 * 16 + rowg * 4 + r;
            const float* hwrow = hw + (size_t)(m & 31) * DIM + n0 + wc * 64;
            const float* vrow  = vvec + n0 + wc * 64;
            float sumv = 0.f;
            #pragma unroll
            for (int j = 0; j < 4; ++j) {
                const int nl = j * 16 + colg;
                float pre = acc[i2][j][r] + hwrow[nl];
                sumv += vrow[nl] * fast_tanh(pre);
            }
            sumv += __shfl_xor(sumv, 1);
            sumv += __shfl_xor(sumv, 2);
            sumv += __shfl_xor(sumv, 4);
            sumv += __shfl_xor(sumv, 8);
            if (colg == 0) partials[(size_t)m * 16 + nb * 2 + wc] = sumv;
        }
}

// per-batch softmax over s (sums the 16 partials per (s,b) first); 1024 thr, 2 s each
__global__ __launch_bounds__(1024) void k_softmax(const float* __restrict__ partials,
                                                  float* __restrict__ out) {
    const int b = blockIdx.x;      // 32
    const int tid = threadIdx.x;   // 1024
    __shared__ float redm[16], reds[16];
    float loc[2];
    float mx = -1e30f;
    #pragma unroll
    for (int i = 0; i < 2; ++i) {
        const int s = tid + i * 1024;
        const float4* p = (const float4*)(partials + ((size_t)s * 32 + b) * 16);
        float4 p0 = p[0], p1 = p[1], p2 = p[2], p3 = p[3];
        float v = ((p0.x + p0.y) + (p0.z + p0.w)) + ((p1.x + p1.y) + (p1.z + p1.w))
                + ((p2.x + p2.y) + (p2.z + p2.w)) + ((p3.x + p3.y) + (p3.z + p3.w));
        loc[i] = v; mx = fmaxf(mx, v);
    }
    #pragma unroll
    for (int o = 32; o; o >>= 1) mx = fmaxf(mx, __shfl_xor(mx, o));
    const int wid2 = tid >> 6, lane = tid & 63;
    if (lane == 0) redm[wid2] = mx;
    __syncthreads();
    mx = redm[0];
    #pragma unroll
    for (int w = 1; w < 16; ++w) mx = fmaxf(mx, redm[w]);
    float sum = 0.f;
    #pragma unroll
    for (int i = 0; i < 2; ++i) { float e = __expf(loc[i] - mx); loc[i] = e; sum += e; }
    #pragma unroll
    for (int o = 32; o; o >>= 1) sum += __shfl_xor(sum, o);
    if (lane == 0) reds[wid2] = sum;
    __syncthreads();
    sum = 0.f;
    #pragma unroll
    for (int w = 0; w < 16; ++w) sum += reds[w];
    const float rs = 1.0f / sum;
    #pragma unroll
    for (int i = 0; i < 2; ++i) out[(size_t)b * S_LEN + tid + i * 1024] = loc[i] * rs;
}

extern "C" void kernel_launch(void* const* d_in, const int* in_sizes, int n_in,
                              void* d_out, int out_size, void* d_ws, size_t ws_size,
                              hipStream_t stream) {
    const float* hidden = (const float*)d_in[0];
    const float* enc    = (const float*)d_in[1];
    const float* attn_w = (const float*)d_in[2];
    const float* attn_b = (const float*)d_in[3];
    const float* v      = (const float*)d_in[4];
    float* out = (float*)d_out;

    char* ws = (char*)d_ws;
    float*          hw       = (float*)ws;                                   // 128 KiB
    unsigned short* w2bf     = (unsigned short*)(ws + (128u << 10));         // 2 MiB
    float*          partials = (float*)(ws + (128u << 10) + (2u << 20));     // 4 MiB
    unsigned short* encbf    = (unsigned short*)(ws + (128u << 10) + (6u << 20)); // 128 MiB
    const size_t NEED = (128u << 10) + (6u << 20) + ((size_t)S_LEN * BATCH * DIM * 2);

    if (ws_size >= NEED) {
        hipLaunchKernelGGL(k_prep, dim3(6144), dim3(256), 0, stream,
                           enc, encbf, attn_w, w2bf, hidden, attn_b, hw);
        hipLaunchKernelGGL(k_main, dim3(4096), dim3(256), 0, stream, encbf, w2bf, hw, v, partials);
    } else {
        hipLaunchKernelGGL(k_prep, dim3(6144), dim3(256), 0, stream,
                           enc, (unsigned short*)w2bf, attn_w, w2bf, hidden, attn_b, hw);
        hipLaunchKernelGGL(k_main_f32, dim3(4096), dim3(256), 0, stream, enc, w2bf, hw, v, partials);
    }
    hipLaunchKernelGGL(k_softmax, dim3(32), dim3(1024), 0, stream, partials, out);
}